// Round 2
// baseline (413.368 us; speedup 1.0000x reference)
//
#include <hip/hip_runtime.h>
#include <math.h>

typedef __bf16 bfrag __attribute__((ext_vector_type(8)));
typedef __bf16 bf16x4 __attribute__((ext_vector_type(4)));
typedef __bf16 bf16x8 __attribute__((ext_vector_type(8)));
typedef float f32x4 __attribute__((ext_vector_type(4)));

// Problem constants
#define BN 32
#define HH 300
#define WW 300
#define HW 90000
#define NPX (BN * HW)

// Output tile 16x16
#define GX 19   // ceil(300/16)
#define GY 19
#define CPX 324 // 18*18 c-tile pixels
#define XPX 400 // 20*20 staged pixels
#define CWSTRIDE 2592  // 324*8 shorts per channel-block array

// Workspace layout (bytes)
#define P5I_BYTE_OFF   0         // [32][3600][8] bf16 = 1,843,200
#define P10I_BYTE_OFF  1843200   // [32][900][8]  bf16 = 460,800
#define P15I_BYTE_OFF  2304000   // [32][400][8]  bf16 = 204,800
#define CWB_BYTE_OFF   2508800   // [3][16][10][16] bf16 = 15,360
#define GWB_BYTE_OFF   2524160   // [16][28][8] bf16 = 7,168
#define STAT_BYTE_OFF  2531328   // [16][64] doubles = 8,192
#define SS_BYTE_OFF    2539520   // 16 floats
#define XBF_BYTE_OFF   2539584   // [32][90000][8] bf16 = 46,080,000 (optional)
#define XBF_END        (XBF_BYTE_OFF + (size_t)NPX * 16)

__device__ __forceinline__ short f2bf(float f) {
    union { float f; unsigned u; } v;
    v.f = f;
    unsigned r = v.u + 0x7FFF + ((v.u >> 16) & 1);
    return (short)(r >> 16);
}

__device__ __forceinline__ float bf2f(unsigned short s) {
    union { unsigned u; float f; } v;
    v.u = ((unsigned)s) << 16;
    return v.f;
}

// ---------------------------------------------------------------------------
// K0: build bf16 MFMA weight layouts + zero BN stat bins
// cB[s][n16][tap10][ci16]  (n>=8, tap==9 -> 0);  gB[n16][blk28][cj8] (blk>=27 -> 0)
// ---------------------------------------------------------------------------
__global__ void k_setup(const float* __restrict__ w5, const float* __restrict__ w10,
                        const float* __restrict__ w15, const float* __restrict__ gw,
                        const float* __restrict__ mw, short* __restrict__ cBg,
                        short* __restrict__ gBg, double* __restrict__ stats) {
    int t = threadIdx.x;
    for (int idx = t; idx < 7680; idx += 256) {
        int s = idx / 2560, rem = idx % 2560;
        int n = rem / 160, r2 = rem % 160;
        int tap = r2 / 16, ci = r2 % 16;
        float v = 0.f;
        if (n < 8 && tap < 9) {
            const float* W = (s == 0) ? w5 : ((s == 1) ? w10 : w15);
            v = W[(n * 16 + ci) * 9 + tap];
        }
        cBg[idx] = f2bf(v);
    }
    for (int idx = t; idx < 3584; idx += 256) {
        int n = idx / 224, r2 = idx % 224;
        int blk = r2 / 8, cj = r2 % 8;
        float v = 0.f;
        if (blk < 27) {
            int tap = blk / 3, ci24 = (blk % 3) * 8 + cj;
            if (n < 8) v = gw[(n * 24 + ci24) * 9 + tap];
            else       v = mw[((n - 8) * 24 + ci24) * 9 + tap];
        }
        gBg[idx] = f2bf(v);
    }
    for (int idx = t; idx < 16 * 64; idx += 256) stats[idx] = 0.0;
}

// ---------------------------------------------------------------------------
// K1 (fallback, when workspace too small for xbf): 5x5 pool, scalar reads
// ---------------------------------------------------------------------------
__global__ void k_pool5(const float* __restrict__ x, unsigned short* __restrict__ p5i) {
    int id = blockIdx.x * 256 + threadIdx.x;  // < 921600
    int bc = id / 3600, cell = id % 3600;
    int b = bc >> 3, c = bc & 7;
    int pi = cell / 60, pj = cell % 60;
    const float* rp = x + (size_t)bc * HW + pi * 5 * WW + pj * 5;
    float s = 0.f;
#pragma unroll
    for (int u = 0; u < 5; u++)
#pragma unroll
        for (int v = 0; v < 5; v++) s += rp[u * WW + v];
    p5i[((size_t)b * 3600 + cell) * 8 + c] = (unsigned short)f2bf(s * 0.04f);
}

// ---------------------------------------------------------------------------
// K1': fused prep — coalesced f32 loads into LDS, then (a) channel-interleaved
// bf16 copy of x (xbf) and (b) the 5x5 pool.
// ---------------------------------------------------------------------------
__global__ __launch_bounds__(256) void k_prep(const float* __restrict__ x,
                                              unsigned short* __restrict__ xbf,
                                              unsigned short* __restrict__ p5i) {
    __shared__ float tf[8][5][304];
    const int t = threadIdx.x;
    const int pi = blockIdx.x, b = blockIdx.y;
    for (int idx = t; idx < 3000; idx += 256) {
        int ch = idx / 375, rem = idx % 375;
        int r = rem / 75, j = rem % 75;
        float4 v = *(const float4*)&x[((size_t)(b * 8 + ch) * HH + pi * 5 + r) * WW + 4 * j];
        *(float4*)&tf[ch][r][4 * j] = v;
    }
    __syncthreads();
    for (int idx = t; idx < 1500; idx += 256) {
        int r = idx / 300, c = idx - r * 300;
        bf16x8 pk;
#pragma unroll
        for (int ch = 0; ch < 8; ch++) pk[ch] = (__bf16)tf[ch][r][c];
        *(bf16x8*)&xbf[((size_t)b * HW + (pi * 5 + r) * WW + c) * 8] = pk;
    }
    for (int idx = t; idx < 512; idx += 256) {
        int ch = idx >> 6, pj = idx & 63;
        if (pj < 60) {
            float s = 0.f;
#pragma unroll
            for (int u = 0; u < 5; u++)
#pragma unroll
                for (int v = 0; v < 5; v++) s += tf[ch][u][pj * 5 + v];
            p5i[((size_t)b * 3600 + pi * 60 + pj) * 8 + ch] = (unsigned short)f2bf(s * 0.04f);
        }
    }
}

// ---------------------------------------------------------------------------
// K1b: derive 10x10 and 15x15 pools from p5i (L2-hot, tiny)
// ---------------------------------------------------------------------------
__global__ void k_poolD(const unsigned short* __restrict__ p5i,
                        unsigned short* __restrict__ p10i,
                        unsigned short* __restrict__ p15i) {
    int id = blockIdx.x * 256 + threadIdx.x;
    if (id < 230400) {  // p10: (b,ch) x 900 cells
        int bc = id / 900, cell = id % 900;
        int b = bc >> 3, c = bc & 7;
        int pi = cell / 30, pj = cell % 30;
        const unsigned short* base = p5i + ((size_t)b * 3600) * 8 + c;
        float s = bf2f(base[((2 * pi) * 60 + 2 * pj) * 8]) +
                  bf2f(base[((2 * pi) * 60 + 2 * pj + 1) * 8]) +
                  bf2f(base[((2 * pi + 1) * 60 + 2 * pj) * 8]) +
                  bf2f(base[((2 * pi + 1) * 60 + 2 * pj + 1) * 8]);
        p10i[((size_t)b * 900 + cell) * 8 + c] = (unsigned short)f2bf(s * 0.25f);
    } else if (id < 332800) {  // p15: (b,ch) x 400 cells
        int id2 = id - 230400;
        int bc = id2 / 400, cell = id2 % 400;
        int b = bc >> 3, c = bc & 7;
        int pi = cell / 20, pj = cell % 20;
        const unsigned short* base = p5i + ((size_t)b * 3600) * 8 + c;
        float s = 0.f;
#pragma unroll
        for (int u = 0; u < 3; u++)
#pragma unroll
            for (int v = 0; v < 3; v++)
                s += bf2f(base[((3 * pi + u) * 60 + 3 * pj + v) * 8]);
        p15i[((size_t)b * 400 + cell) * 8 + c] = (unsigned short)f2bf(s * (1.f / 9.f));
    }
}

// ---------------------------------------------------------------------------
// up-channel staging, software-pipelined (20x20 = 400 pixels, 2 iters)
// ---------------------------------------------------------------------------
template <int K, int PW>
__device__ __forceinline__ void up_load(const unsigned short* __restrict__ pooled,
                                        int b, int r0, int c0, int t, uint4* v) {
#pragma unroll
    for (int it = 0; it < 2; it++) {
        int idx = t + 256 * it;
        uint4 val = {0u, 0u, 0u, 0u};
        if (idx < XPX) {
            int i = idx / 20, j = idx - i * 20;
            int ra = r0 - 2 + i, ca = c0 - 2 + j;
            if (ra >= 0 && ra < HH && ca >= 0 && ca < WW) {
                int pi = (int)((unsigned)ra / K);
                int pj = (int)((unsigned)ca / K);
                val = *(const uint4*)&pooled[((size_t)b * (PW * PW) + pi * PW + pj) * 8];
            }
        }
        v[it] = val;
    }
}

__device__ __forceinline__ void up_store(short* xuU, int t, const uint4* v) {
#pragma unroll
    for (int it = 0; it < 2; it++) {
        int idx = t + 256 * it;
        if (idx < XPX) *(uint4*)&xuU[idx * 8] = v[it];
    }
}

// ---------------------------------------------------------------------------
// c-phase: conv([x, up_s]) over 18x18 c-tile, operand-swapped MFMA.
// Output goes to channel-block-major cwP = cwS + s*CWSTRIDE: [px][8ch],
// 16B/pixel -> lane-contiguous writes, conflict-free, and the gate phase's
// B-fragment reads become contiguous too (no 48B-stride aliasing).
// ---------------------------------------------------------------------------
__device__ __forceinline__ void c_phase(const short* xuX, const short* xuU,
                                        short* cwP,
                                        const unsigned short* __restrict__ cBs,
                                        const float* __restrict__ bias,
                                        int r0, int c0, int lane, int wid, bool edge) {
    const int n = lane & 15, quad = lane >> 4;
    const int qh = quad >> 1, ql = quad & 1;
    const short* xbase = ql ? xuU : xuX;
    bfrag wfr[5];
    int dpoff[5];
#pragma unroll
    for (int km = 0; km < 5; km++) {
        int tapw = km * 2 + qh;                 // 9 -> zero row in cB
        int tapa = (tapw > 8) ? 8 : tapw;       // address clamp only
        wfr[km] = *(const bfrag*)&cBs[(n * 10 + tapw) * 16 + ql * 8];
        dpoff[km] = ((tapa / 3) * 20 + tapa % 3) * 8;  // pixel offset, in shorts
    }
    float bO[4];
#pragma unroll
    for (int r = 0; r < 4; r++) bO[r] = bias[(quad & 1) * 4 + r];

    for (int g = wid; g < 21; g += 4) {
        int px = g * 16 + n;
        if (px > 323) px = 323;                 // dup lanes write same value
        int rp = (int)((unsigned)px / 18u);
        int cp = px - rp * 18;
        int pb = (rp * 20 + cp) * 8;
        f32x4 acc = {0.f, 0.f, 0.f, 0.f};
#pragma unroll
        for (int km = 0; km < 5; km++)
            acc = __builtin_amdgcn_mfma_f32_16x16x32_bf16(
                wfr[km], *(const bfrag*)&xbase[pb + dpoff[km]], acc, 0, 0, 0);
        if (quad < 2) {                          // channels quad*4+reg (0..7)
            bf16x4 pk;
#pragma unroll
            for (int r = 0; r < 4; r++) pk[r] = (__bf16)(acc[r] + bO[r]);
            if (edge) {
                int ra = r0 - 1 + rp, ca = c0 - 1 + cp;
                if (ra < 0 || ra >= HH || ca < 0 || ca >= WW) {
#pragma unroll
                    for (int r = 0; r < 4; r++) pk[r] = (__bf16)0.f;
                }
            }
            *(bf16x4*)&cwP[px * 8 + quad * 4] = pk;
        }
    }
}

// ---------------------------------------------------------------------------
// K2: fused MFMA kernel — one 16x16 output tile per 256-thread block
// LDS = xuX(6400) + xuU(6400) + cwS(15552) = 28.4KB -> 5 blocks/CU (20 waves)
// ---------------------------------------------------------------------------
template <bool XBF>
__global__ __launch_bounds__(256, 5) void k_fused(
    const float* __restrict__ x, const unsigned short* __restrict__ xbf,
    const unsigned short* __restrict__ p5i, const unsigned short* __restrict__ p10i,
    const unsigned short* __restrict__ p15i,
    const unsigned short* __restrict__ cBg, const unsigned short* __restrict__ gBg,
    const float* __restrict__ b5, const float* __restrict__ b10, const float* __restrict__ b15,
    const float* __restrict__ gb, const float* __restrict__ mb,
    float* __restrict__ out, double* __restrict__ stats) {
    __shared__ __align__(16) short xuX[XPX * 8];       // [i20*j20][ci8] x half
    __shared__ __align__(16) short xuU[XPX * 8];       // [i20*j20][ci8] up half
    __shared__ __align__(16) short cwS[3 * CWSTRIDE];  // [s3][px 18*18][ci8]

    const int b = blockIdx.z;
    const int r0 = blockIdx.y * 16, c0 = blockIdx.x * 16;
    const int t = threadIdx.x, lane = t & 63, wid = t >> 6;
    const bool edge = (blockIdx.x == 0) | (blockIdx.x == GX - 1) |
                      (blockIdx.y == 0) | (blockIdx.y == GY - 1);

    // pipeline scale-0 pooled loads early (global->reg, no LDS dep)
    uint4 upv[2];
    up_load<5, 60>(p5i, b, r0, c0, t, upv);

    if constexpr (XBF) {
        // x half from pre-interleaved bf16: one uint4 per pixel
#pragma unroll
        for (int it = 0; it < 2; it++) {
            int idx = t + 256 * it;
            if (idx < XPX) {
                int i = idx / 20, j = idx - i * 20;
                int ra = r0 - 2 + i, ca = c0 - 2 + j;
                uint4 v = {0u, 0u, 0u, 0u};
                if (ra >= 0 && ra < HH && ca >= 0 && ca < WW)
                    v = *(const uint4*)&xbf[((size_t)b * HW + ra * WW + ca) * 8];
                *(uint4*)&xuX[idx * 8] = v;
            }
        }
    } else {
        // f32 pixel-pair staging with in-kernel bf16 conversion (fallback)
        for (int idx = t; idx < 800; idx += 256) {
            int cp = idx / 200, rem = idx % 200;
            int i = rem / 10, jp = rem % 10;
            int j = 2 * jp;
            int ra = r0 - 2 + i, ca = c0 - 2 + j;
            float2 v0 = {0.f, 0.f}, v1 = {0.f, 0.f};
            if (ra >= 0 && ra < HH && ca >= 0 && ca <= WW - 2) {
                size_t base = ((size_t)(b * 8 + 2 * cp) * HH + ra) * WW + ca;
                v0 = *(const float2*)&x[base];
                v1 = *(const float2*)&x[base + HW];
            }
            unsigned pA = (unsigned short)f2bf(v0.x) | ((unsigned)(unsigned short)f2bf(v1.x) << 16);
            unsigned pB = (unsigned short)f2bf(v0.y) | ((unsigned)(unsigned short)f2bf(v1.y) << 16);
            int px = i * 20 + j;
            *(unsigned*)&xuX[px * 8 + 2 * cp] = pA;
            *(unsigned*)&xuX[(px + 1) * 8 + 2 * cp] = pB;
        }
    }
    up_store(xuU, t, upv);
    __syncthreads();

    c_phase(xuX, xuU, cwS, cBg, b5, r0, c0, lane, wid, edge);
    up_load<10, 30>(p10i, b, r0, c0, t, upv);   // overlaps c_phase compute
    __syncthreads();
    up_store(xuU, t, upv);
    __syncthreads();

    c_phase(xuX, xuU, cwS + CWSTRIDE, cBg + 2560, b10, r0, c0, lane, wid, edge);
    up_load<15, 20>(p15i, b, r0, c0, t, upv);
    __syncthreads();
    up_store(xuU, t, upv);
    __syncthreads();

    c_phase(xuX, xuU, cwS + 2 * CWSTRIDE, cBg + 5120, b15, r0, c0, lane, wid, edge);
    __syncthreads();

    // gate phase, operand-swapped: A = gB weights (rows: G 0-7, M 8-15),
    // B = cwS pixels. Group g = output row (scalar), lane n = output col.
    // Sigmoid is evaluated on the M-lanes (quads 2,3) BEFORE the shfl so
    // the expensive chain runs on otherwise-idle lanes.
    const int n = lane & 15, quad = lane >> 4;
    bfrag gfr[7];
    int goff[7];
#pragma unroll
    for (int km = 0; km < 7; km++) {
        int blkw = km * 4 + quad;               // 27 -> zero block in gB
        int blka = (blkw > 26) ? 26 : blkw;     // address clamp only
        gfr[km] = *(const bfrag*)&gBg[(n * 28 + blkw) * 8];
        int tap = blka / 3, cig = blka - tap * 3;
        goff[km] = cig * CWSTRIDE + ((tap / 3) * 18 + tap % 3) * 8;
    }
    float gO[4], mO[4];
#pragma unroll
    for (int r = 0; r < 4; r++) {
        gO[r] = gb[(quad & 1) * 4 + r];
        mO[r] = mb[(quad & 1) * 4 + r];
    }
    float ls[4] = {0.f, 0.f, 0.f, 0.f}, ls2[4] = {0.f, 0.f, 0.f, 0.f};

    for (int g = wid; g < 16; g += 4) {
        int off0 = (g * 18 + n) * 8;
        f32x4 acc = {0.f, 0.f, 0.f, 0.f};
#pragma unroll
        for (int km = 0; km < 7; km++)
            acc = __builtin_amdgcn_mfma_f32_16x16x32_bf16(
                gfr[km], *(const bfrag*)&cwS[off0 + goff[km]], acc, 0, 0, 0);
        int ra = r0 + g, ca = c0 + n;
        bool wr = !edge || (ra < HH && ca < WW);
#pragma unroll
        for (int reg = 0; reg < 4; reg++) {
            float val;
            if (quad < 2) val = acc[reg] + gO[reg];
            else          val = __builtin_amdgcn_rcpf(1.f + __expf(-(acc[reg] + mO[reg])));
            float other = __shfl_xor(val, 32);  // G(quad q) <-> sig(M)(quad q+2)
            if (quad < 2 && wr) {
                float y = val * other;
                int ch = quad * 4 + reg;
                out[(size_t)(b * 8 + ch) * HW + ra * WW + ca] = y;
                ls[reg] += y;
                ls2[reg] += y * y;
            }
        }
    }
    // BN partials: fold over the 16 lanes sharing a channel set, then
    // hashed-bin double atomics
#pragma unroll
    for (int m = 1; m < 16; m <<= 1) {
#pragma unroll
        for (int r = 0; r < 4; r++) {
            ls[r] += __shfl_xor(ls[r], m);
            ls2[r] += __shfl_xor(ls2[r], m);
        }
    }
    if (n == 0 && quad < 2) {
        int hash = (blockIdx.x + GX * blockIdx.y + GX * GY * blockIdx.z) & 63;
#pragma unroll
        for (int r = 0; r < 4; r++) {
            atomicAdd(&stats[(quad * 4 + r) * 64 + hash], (double)ls[r]);
            atomicAdd(&stats[(8 + quad * 4 + r) * 64 + hash], (double)ls2[r]);
        }
    }
}

// ---------------------------------------------------------------------------
__global__ void k_stats(const double* __restrict__ stats, const float* __restrict__ gamma,
                        const float* __restrict__ beta, float* __restrict__ ss) {
    __shared__ double tot[16];
    int t = threadIdx.x;
    if (t < 16) {
        double s = 0.0;
        for (int i = 0; i < 64; i++) s += stats[t * 64 + i];
        tot[t] = s;
    }
    __syncthreads();
    if (t < 8) {
        double N = (double)NPX;
        double mean = tot[t] / N;
        double var = tot[8 + t] / N - mean * mean;
        double scale = (double)gamma[t] / sqrt(var + 1e-5);
        ss[t] = (float)scale;
        ss[8 + t] = (float)((double)beta[t] - mean * scale);
    }
}

// ---------------------------------------------------------------------------
__global__ void k_norm(float* __restrict__ out, const float* __restrict__ ss) {
    int i = blockIdx.x * 256 + threadIdx.x;
    if (i < (BN * 8 * HW) / 4) {
        int plane = (i * 4) / HW;
        int ch = plane & 7;
        float sc = ss[ch], sh = ss[8 + ch];
        float4* p = (float4*)out + i;
        float4 v = *p;
        v.x = v.x * sc + sh;
        v.y = v.y * sc + sh;
        v.z = v.z * sc + sh;
        v.w = v.w * sc + sh;
        *p = v;
    }
}

// ---------------------------------------------------------------------------
extern "C" void kernel_launch(void* const* d_in, const int* in_sizes, int n_in,
                              void* d_out, int out_size, void* d_ws, size_t ws_size,
                              hipStream_t stream) {
    const float* x = (const float*)d_in[0];
    const float* w5 = (const float*)d_in[1];
    const float* b5 = (const float*)d_in[2];
    const float* w10 = (const float*)d_in[3];
    const float* b10 = (const float*)d_in[4];
    const float* w15 = (const float*)d_in[5];
    const float* b15 = (const float*)d_in[6];
    const float* gw = (const float*)d_in[7];
    const float* gb = (const float*)d_in[8];
    const float* mw = (const float*)d_in[9];
    const float* mb = (const float*)d_in[10];
    const float* gamma = (const float*)d_in[11];
    const float* beta = (const float*)d_in[12];

    float* out = (float*)d_out;
    unsigned short* p5i = (unsigned short*)((char*)d_ws + P5I_BYTE_OFF);
    unsigned short* p10i = (unsigned short*)((char*)d_ws + P10I_BYTE_OFF);
    unsigned short* p15i = (unsigned short*)((char*)d_ws + P15I_BYTE_OFF);
    short* cBg = (short*)((char*)d_ws + CWB_BYTE_OFF);
    short* gBg = (short*)((char*)d_ws + GWB_BYTE_OFF);
    double* stats = (double*)((char*)d_ws + STAT_BYTE_OFF);
    float* ss = (float*)((char*)d_ws + SS_BYTE_OFF);
    unsigned short* xbf = (unsigned short*)((char*)d_ws + XBF_BYTE_OFF);

    const bool use_xbf = (ws_size >= XBF_END);

    k_setup<<<1, 256, 0, stream>>>(w5, w10, w15, gw, mw, cBg, gBg, stats);
    if (use_xbf) {
        k_prep<<<dim3(60, 32), 256, 0, stream>>>(x, xbf, p5i);
    } else {
        k_pool5<<<3600, 256, 0, stream>>>(x, p5i);
    }
    k_poolD<<<1300, 256, 0, stream>>>(p5i, p10i, p15i);
    dim3 grid(GX, GY, BN);
    if (use_xbf) {
        k_fused<true><<<grid, 256, 0, stream>>>(x, xbf, p5i, p10i, p15i,
                                                (const unsigned short*)cBg, (const unsigned short*)gBg,
                                                b5, b10, b15, gb, mb, out, stats);
    } else {
        k_fused<false><<<grid, 256, 0, stream>>>(x, xbf, p5i, p10i, p15i,
                                                 (const unsigned short*)cBg, (const unsigned short*)gBg,
                                                 b5, b10, b15, gb, mb, out, stats);
    }
    k_stats<<<1, 64, 0, stream>>>(stats, gamma, beta, ss);
    k_norm<<<(BN * 8 * HW / 4 + 255) / 256, 256, 0, stream>>>(out, ss);
}

// Round 4
// 387.387 us; speedup vs baseline: 1.0671x; 1.0671x over previous
//
#include <hip/hip_runtime.h>
#include <math.h>

typedef __bf16 bfrag __attribute__((ext_vector_type(8)));
typedef __bf16 bf16x4 __attribute__((ext_vector_type(4)));
typedef __bf16 bf16x8 __attribute__((ext_vector_type(8)));
typedef float f32x4 __attribute__((ext_vector_type(4)));

// Problem constants
#define BN 32
#define HH 300
#define WW 300
#define HW 90000
#define NPX (BN * HW)

// Output tile 16 rows x 32 cols
#define GX 10   // ceil(300/32)
#define GY 19   // ceil(300/16)
#define CPX 612         // 18*34 c-tile pixels
#define XPX 720         // 20*36 staged pixels
#define CWSTRIDE 4896   // 612*8 shorts per channel-block array

// Workspace layout (bytes)
#define P5I_BYTE_OFF   0         // [32][3600][8] bf16 = 1,843,200
#define P10I_BYTE_OFF  1843200   // [32][900][8]  bf16 = 460,800
#define P15I_BYTE_OFF  2304000   // [32][400][8]  bf16 = 204,800
#define CWB_BYTE_OFF   2508800   // [3][16][10][16] bf16 = 15,360
#define GWB_BYTE_OFF   2524160   // [16][28][8] bf16 = 7,168
#define STAT_BYTE_OFF  2531328   // [16][64] doubles = 8,192
#define SS_BYTE_OFF    2539520   // 16 floats
#define XBF_BYTE_OFF   2539584   // [32][90000][8] bf16 = 46,080,000 (optional)
#define XBF_END        (XBF_BYTE_OFF + (size_t)NPX * 16)

__device__ __forceinline__ short f2bf(float f) {
    union { float f; unsigned u; } v;
    v.f = f;
    unsigned r = v.u + 0x7FFF + ((v.u >> 16) & 1);
    return (short)(r >> 16);
}

__device__ __forceinline__ float bf2f(unsigned short s) {
    union { unsigned u; float f; } v;
    v.u = ((unsigned)s) << 16;
    return v.f;
}

// ---------------------------------------------------------------------------
// setup work (shared by k_setup fallback and k_xbf fold-in):
// cB[s][n16][tap10][ci16]  (n>=8, tap==9 -> 0);  gB[n16][blk28][cj8] (blk>=27 -> 0)
// ---------------------------------------------------------------------------
__device__ __forceinline__ void setup_body(int gid, int gstride,
                                           const float* __restrict__ w5,
                                           const float* __restrict__ w10,
                                           const float* __restrict__ w15,
                                           const float* __restrict__ gw,
                                           const float* __restrict__ mw,
                                           short* __restrict__ cBg,
                                           short* __restrict__ gBg,
                                           double* __restrict__ stats) {
    for (int idx = gid; idx < 7680; idx += gstride) {
        int s = idx / 2560, rem = idx % 2560;
        int n = rem / 160, r2 = rem % 160;
        int tap = r2 / 16, ci = r2 % 16;
        float v = 0.f;
        if (n < 8 && tap < 9) {
            const float* W = (s == 0) ? w5 : ((s == 1) ? w10 : w15);
            v = W[(n * 16 + ci) * 9 + tap];
        }
        cBg[idx] = f2bf(v);
    }
    for (int idx = gid; idx < 3584; idx += gstride) {
        int n = idx / 224, r2 = idx % 224;
        int blk = r2 / 8, cj = r2 % 8;
        float v = 0.f;
        if (blk < 27) {
            int tap = blk / 3, ci24 = (blk % 3) * 8 + cj;
            if (n < 8) v = gw[(n * 24 + ci24) * 9 + tap];
            else       v = mw[((n - 8) * 24 + ci24) * 9 + tap];
        }
        gBg[idx] = f2bf(v);
    }
    for (int idx = gid; idx < 16 * 64; idx += gstride) stats[idx] = 0.0;
}

__global__ void k_setup(const float* __restrict__ w5, const float* __restrict__ w10,
                        const float* __restrict__ w15, const float* __restrict__ gw,
                        const float* __restrict__ mw, short* __restrict__ cBg,
                        short* __restrict__ gBg, double* __restrict__ stats) {
    setup_body(threadIdx.x, 256, w5, w10, w15, gw, mw, cBg, gBg, stats);
}

// ---------------------------------------------------------------------------
// k_xbf: build channel-interleaved bf16 copy of x. Thread = pixel; the 8
// per-channel f32 loads are each fully coalesced across lanes (stride HW
// between them). Blocks (0..15, y==0) also fold in the setup work (its
// consumers are later dispatches -> no race).
// ---------------------------------------------------------------------------
__global__ __launch_bounds__(256) void k_xbf(const float* __restrict__ x,
                                             unsigned short* __restrict__ xbf,
                                             const float* __restrict__ w5,
                                             const float* __restrict__ w10,
                                             const float* __restrict__ w15,
                                             const float* __restrict__ gw,
                                             const float* __restrict__ mw,
                                             short* __restrict__ cBg,
                                             short* __restrict__ gBg,
                                             double* __restrict__ stats) {
    const int b = blockIdx.y;
    const int px = blockIdx.x * 256 + threadIdx.x;
    if (px < HW) {
        const float* xp = x + (size_t)b * 8 * HW + px;
        bf16x8 pk;
#pragma unroll
        for (int ch = 0; ch < 8; ch++) pk[ch] = (__bf16)xp[(size_t)ch * HW];
        *(bf16x8*)&xbf[((size_t)b * HW + px) * 8] = pk;
    }
    if (blockIdx.y == 0 && blockIdx.x < 16) {
        int gid = blockIdx.x * 256 + threadIdx.x;
        setup_body(gid, 4096, w5, w10, w15, gw, mw, cBg, gBg, stats);
    }
}

// ---------------------------------------------------------------------------
// K1 (fallback, when workspace too small for xbf): 5x5 pool, scalar reads
// ---------------------------------------------------------------------------
__global__ void k_pool5(const float* __restrict__ x, unsigned short* __restrict__ p5i) {
    int id = blockIdx.x * 256 + threadIdx.x;  // < 921600
    int bc = id / 3600, cell = id % 3600;
    int b = bc >> 3, c = bc & 7;
    int pi = cell / 60, pj = cell % 60;
    const float* rp = x + (size_t)bc * HW + pi * 5 * WW + pj * 5;
    float s = 0.f;
#pragma unroll
    for (int u = 0; u < 5; u++)
#pragma unroll
        for (int v = 0; v < 5; v++) s += rp[u * WW + v];
    p5i[((size_t)b * 3600 + cell) * 8 + c] = (unsigned short)f2bf(s * 0.04f);
}

// ---------------------------------------------------------------------------
// k_pool5b: 5x5 pool from the interleaved bf16 copy (46MB read, all 8
// channels per thread, 16B loads).
// ---------------------------------------------------------------------------
__global__ __launch_bounds__(256) void k_pool5b(const unsigned short* __restrict__ xbf,
                                                unsigned short* __restrict__ p5i) {
    int id = blockIdx.x * 256 + threadIdx.x;   // < 115200
    int b = id / 3600, cell = id % 3600;
    int pi = cell / 60, pj = cell % 60;
    const unsigned short* base = xbf + ((size_t)b * HW + pi * 5 * WW + pj * 5) * 8;
    float s[8] = {0.f, 0.f, 0.f, 0.f, 0.f, 0.f, 0.f, 0.f};
#pragma unroll
    for (int u = 0; u < 5; u++)
#pragma unroll
        for (int v = 0; v < 5; v++) {
            bf16x8 vv = *(const bf16x8*)&base[(u * WW + v) * 8];
#pragma unroll
            for (int ch = 0; ch < 8; ch++) s[ch] += (float)vv[ch];
        }
    bf16x8 pk;
#pragma unroll
    for (int ch = 0; ch < 8; ch++) pk[ch] = (__bf16)(s[ch] * 0.04f);
    *(bf16x8*)&p5i[((size_t)b * 3600 + cell) * 8] = pk;
}

// ---------------------------------------------------------------------------
// K1b: derive 10x10 and 15x15 pools from p5i (L2-hot, tiny)
// ---------------------------------------------------------------------------
__global__ void k_poolD(const unsigned short* __restrict__ p5i,
                        unsigned short* __restrict__ p10i,
                        unsigned short* __restrict__ p15i) {
    int id = blockIdx.x * 256 + threadIdx.x;
    if (id < 230400) {  // p10: (b,ch) x 900 cells
        int bc = id / 900, cell = id % 900;
        int b = bc >> 3, c = bc & 7;
        int pi = cell / 30, pj = cell % 30;
        const unsigned short* base = p5i + ((size_t)b * 3600) * 8 + c;
        float s = bf2f(base[((2 * pi) * 60 + 2 * pj) * 8]) +
                  bf2f(base[((2 * pi) * 60 + 2 * pj + 1) * 8]) +
                  bf2f(base[((2 * pi + 1) * 60 + 2 * pj) * 8]) +
                  bf2f(base[((2 * pi + 1) * 60 + 2 * pj + 1) * 8]);
        p10i[((size_t)b * 900 + cell) * 8 + c] = (unsigned short)f2bf(s * 0.25f);
    } else if (id < 332800) {  // p15: (b,ch) x 400 cells
        int id2 = id - 230400;
        int bc = id2 / 400, cell = id2 % 400;
        int b = bc >> 3, c = bc & 7;
        int pi = cell / 20, pj = cell % 20;
        const unsigned short* base = p5i + ((size_t)b * 3600) * 8 + c;
        float s = 0.f;
#pragma unroll
        for (int u = 0; u < 3; u++)
#pragma unroll
            for (int v = 0; v < 3; v++)
                s += bf2f(base[((3 * pi + u) * 60 + 3 * pj + v) * 8]);
        p15i[((size_t)b * 400 + cell) * 8 + c] = (unsigned short)f2bf(s * (1.f / 9.f));
    }
}

// ---------------------------------------------------------------------------
// up-channel staging, software-pipelined (20x36 = 720 pixels, 3 iters)
// ---------------------------------------------------------------------------
template <int K, int PW>
__device__ __forceinline__ void up_load(const unsigned short* __restrict__ pooled,
                                        int b, int r0, int c0, int t, uint4* v) {
#pragma unroll
    for (int it = 0; it < 3; it++) {
        int idx = t + 256 * it;
        uint4 val = {0u, 0u, 0u, 0u};
        if (idx < XPX) {
            int i = idx / 36, j = idx - i * 36;
            int ra = r0 - 2 + i, ca = c0 - 2 + j;
            if (ra >= 0 && ra < HH && ca >= 0 && ca < WW) {
                int pi = (int)((unsigned)ra / K);
                int pj = (int)((unsigned)ca / K);
                val = *(const uint4*)&pooled[((size_t)b * (PW * PW) + pi * PW + pj) * 8];
            }
        }
        v[it] = val;
    }
}

__device__ __forceinline__ void up_store(short* xuU, int t, const uint4* v) {
#pragma unroll
    for (int it = 0; it < 3; it++) {
        int idx = t + 256 * it;
        if (idx < XPX) *(uint4*)&xuU[idx * 8] = v[it];
    }
}

// ---------------------------------------------------------------------------
// c-phase: conv([x, up_s]) over 18x34 c-tile, operand-swapped MFMA.
// Output goes to channel-block-major cwP = cwS + s*CWSTRIDE: [px][8ch],
// 16B/pixel -> lane-contiguous writes/reads (no 48B-stride aliasing).
// ---------------------------------------------------------------------------
__device__ __forceinline__ void c_phase(const short* xuX, const short* xuU,
                                        short* cwP,
                                        const unsigned short* __restrict__ cBs,
                                        const float* __restrict__ bias,
                                        int r0, int c0, int lane, int wid, bool edge) {
    const int n = lane & 15, quad = lane >> 4;
    const int qh = quad >> 1, ql = quad & 1;
    const short* xbase = ql ? xuU : xuX;
    bfrag wfr[5];
    int dpoff[5];
#pragma unroll
    for (int km = 0; km < 5; km++) {
        int tapw = km * 2 + qh;                 // 9 -> zero row in cB
        int tapa = (tapw > 8) ? 8 : tapw;       // address clamp only
        wfr[km] = *(const bfrag*)&cBs[(n * 10 + tapw) * 16 + ql * 8];
        dpoff[km] = ((tapa / 3) * 36 + tapa % 3) * 8;  // pixel offset, in shorts
    }
    float bO[4];
#pragma unroll
    for (int r = 0; r < 4; r++) bO[r] = bias[(quad & 1) * 4 + r];

    for (int g = wid; g < 39; g += 4) {
        int px = g * 16 + n;
        if (px > 611) px = 611;                 // dup lanes write same value
        int rp = (int)((unsigned)px / 34u);
        int cp = px - rp * 34;
        int pb = (rp * 36 + cp) * 8;
        f32x4 acc = {0.f, 0.f, 0.f, 0.f};
#pragma unroll
        for (int km = 0; km < 5; km++)
            acc = __builtin_amdgcn_mfma_f32_16x16x32_bf16(
                wfr[km], *(const bfrag*)&xbase[pb + dpoff[km]], acc, 0, 0, 0);
        if (quad < 2) {                          // channels quad*4+reg (0..7)
            bf16x4 pk;
#pragma unroll
            for (int r = 0; r < 4; r++) pk[r] = (__bf16)(acc[r] + bO[r]);
            if (edge) {
                int ra = r0 - 1 + rp, ca = c0 - 1 + cp;
                if (ra < 0 || ra >= HH || ca < 0 || ca >= WW) {
#pragma unroll
                    for (int r = 0; r < 4; r++) pk[r] = (__bf16)0.f;
                }
            }
            *(bf16x4*)&cwP[px * 8 + quad * 4] = pk;
        }
    }
}

// ---------------------------------------------------------------------------
// K2: fused MFMA kernel — one 16x32 output tile per 256-thread block
// LDS = xuX(11520) + xuU(11520) + cwS(29376) = 52.4KB -> 3 blocks/CU
// ---------------------------------------------------------------------------
template <bool XBF>
__global__ __launch_bounds__(256, 3) void k_fused(
    const float* __restrict__ x, const unsigned short* __restrict__ xbf,
    const unsigned short* __restrict__ p5i, const unsigned short* __restrict__ p10i,
    const unsigned short* __restrict__ p15i,
    const unsigned short* __restrict__ cBg, const unsigned short* __restrict__ gBg,
    const float* __restrict__ b5, const float* __restrict__ b10, const float* __restrict__ b15,
    const float* __restrict__ gb, const float* __restrict__ mb,
    float* __restrict__ out, double* __restrict__ stats) {
    __shared__ __align__(16) short xuX[XPX * 8];       // [i20*j36][ci8] x half
    __shared__ __align__(16) short xuU[XPX * 8];       // [i20*j36][ci8] up half
    __shared__ __align__(16) short cwS[3 * CWSTRIDE];  // [s3][px 18*34][ci8]

    const int b = blockIdx.z;
    const int r0 = blockIdx.y * 16, c0 = blockIdx.x * 32;
    const int t = threadIdx.x, lane = t & 63, wid = t >> 6;
    const bool edge = (blockIdx.x == 0) | (blockIdx.x == GX - 1) |
                      (blockIdx.y == 0) | (blockIdx.y == GY - 1);

    // pipeline scale-0 pooled loads early (global->reg, no LDS dep)
    uint4 upv[3];
    up_load<5, 60>(p5i, b, r0, c0, t, upv);

    if constexpr (XBF) {
        // x half from pre-interleaved bf16: one uint4 per pixel
#pragma unroll
        for (int it = 0; it < 3; it++) {
            int idx = t + 256 * it;
            if (idx < XPX) {
                int i = idx / 36, j = idx - i * 36;
                int ra = r0 - 2 + i, ca = c0 - 2 + j;
                uint4 v = {0u, 0u, 0u, 0u};
                if (ra >= 0 && ra < HH && ca >= 0 && ca < WW)
                    v = *(const uint4*)&xbf[((size_t)b * HW + ra * WW + ca) * 8];
                *(uint4*)&xuX[idx * 8] = v;
            }
        }
    } else {
        // f32 pixel-pair staging with in-kernel bf16 conversion (fallback)
        for (int idx = t; idx < 1440; idx += 256) {
            int cp = idx / 360, rem = idx % 360;
            int i = rem / 18, jp = rem % 18;
            int j = 2 * jp;
            int ra = r0 - 2 + i, ca = c0 - 2 + j;
            float2 v0 = {0.f, 0.f}, v1 = {0.f, 0.f};
            if (ra >= 0 && ra < HH && ca >= 0 && ca <= WW - 2) {
                size_t base = ((size_t)(b * 8 + 2 * cp) * HH + ra) * WW + ca;
                v0 = *(const float2*)&x[base];
                v1 = *(const float2*)&x[base + HW];
            }
            unsigned pA = (unsigned short)f2bf(v0.x) | ((unsigned)(unsigned short)f2bf(v1.x) << 16);
            unsigned pB = (unsigned short)f2bf(v0.y) | ((unsigned)(unsigned short)f2bf(v1.y) << 16);
            int px = i * 36 + j;
            *(unsigned*)&xuX[px * 8 + 2 * cp] = pA;
            *(unsigned*)&xuX[(px + 1) * 8 + 2 * cp] = pB;
        }
    }
    up_store(xuU, t, upv);
    __syncthreads();

    c_phase(xuX, xuU, cwS, cBg, b5, r0, c0, lane, wid, edge);
    up_load<10, 30>(p10i, b, r0, c0, t, upv);   // overlaps c_phase compute
    __syncthreads();
    up_store(xuU, t, upv);
    __syncthreads();

    c_phase(xuX, xuU, cwS + CWSTRIDE, cBg + 2560, b10, r0, c0, lane, wid, edge);
    up_load<15, 20>(p15i, b, r0, c0, t, upv);
    __syncthreads();
    up_store(xuU, t, upv);
    __syncthreads();

    c_phase(xuX, xuU, cwS + 2 * CWSTRIDE, cBg + 5120, b15, r0, c0, lane, wid, edge);
    __syncthreads();

    // gate phase, operand-swapped: A = gB weights (rows: G 0-7, M 8-15),
    // B = cwS pixels. Sigmoid evaluated on the M-lanes (quads 2,3) BEFORE
    // the shfl so the expensive chain runs on otherwise-idle lanes.
    const int n = lane & 15, quad = lane >> 4;
    bfrag gfr[7];
    int goff[7];
#pragma unroll
    for (int km = 0; km < 7; km++) {
        int blkw = km * 4 + quad;               // 27 -> zero block in gB
        int blka = (blkw > 26) ? 26 : blkw;     // address clamp only
        gfr[km] = *(const bfrag*)&gBg[(n * 28 + blkw) * 8];
        int tap = blka / 3, cig = blka - tap * 3;
        goff[km] = cig * CWSTRIDE + ((tap / 3) * 34 + tap % 3) * 8;
    }
    float gO[4], mO[4];
#pragma unroll
    for (int r = 0; r < 4; r++) {
        gO[r] = gb[(quad & 1) * 4 + r];
        mO[r] = mb[(quad & 1) * 4 + r];
    }
    float ls[4] = {0.f, 0.f, 0.f, 0.f}, ls2[4] = {0.f, 0.f, 0.f, 0.f};

    for (int g = wid; g < 32; g += 4) {
        int px = g * 16 + n;                    // 0..511 within 16x32 tile
        int rr = px >> 5, cc = px & 31;
        int off0 = (rr * 34 + cc) * 8;
        f32x4 acc = {0.f, 0.f, 0.f, 0.f};
#pragma unroll
        for (int km = 0; km < 7; km++)
            acc = __builtin_amdgcn_mfma_f32_16x16x32_bf16(
                gfr[km], *(const bfrag*)&cwS[off0 + goff[km]], acc, 0, 0, 0);
        int ra = r0 + rr, ca = c0 + cc;
        bool wr = !edge || (ra < HH && ca < WW);
#pragma unroll
        for (int reg = 0; reg < 4; reg++) {
            float val;
            if (quad < 2) val = acc[reg] + gO[reg];
            else          val = __builtin_amdgcn_rcpf(1.f + __expf(-(acc[reg] + mO[reg])));
            float other = __shfl_xor(val, 32);  // G(quad q) <-> sig(M)(quad q+2)
            if (quad < 2 && wr) {
                float y = val * other;
                int ch = quad * 4 + reg;
                out[(size_t)(b * 8 + ch) * HW + (size_t)ra * WW + ca] = y;
                ls[reg] += y;
                ls2[reg] += y * y;
            }
        }
    }
    // BN partials: fold over the 16 lanes sharing a channel set, then
    // hashed-bin double atomics
#pragma unroll
    for (int m = 1; m < 16; m <<= 1) {
#pragma unroll
        for (int r = 0; r < 4; r++) {
            ls[r] += __shfl_xor(ls[r], m);
            ls2[r] += __shfl_xor(ls2[r], m);
        }
    }
    if (n == 0 && quad < 2) {
        int hash = (blockIdx.x + GX * blockIdx.y + GX * GY * blockIdx.z) & 63;
#pragma unroll
        for (int r = 0; r < 4; r++) {
            atomicAdd(&stats[(quad * 4 + r) * 64 + hash], (double)ls[r]);
            atomicAdd(&stats[(8 + quad * 4 + r) * 64 + hash], (double)ls2[r]);
        }
    }
}

// ---------------------------------------------------------------------------
// k_stats: 256 threads (16 bins x 16 lanes-per-row partials)
// ---------------------------------------------------------------------------
__global__ void k_stats(const double* __restrict__ stats, const float* __restrict__ gamma,
                        const float* __restrict__ beta, float* __restrict__ ss) {
    __shared__ double red[16][16];
    int t = threadIdx.x;
    int row = t >> 4, col = t & 15;
    double s = stats[row * 64 + col] + stats[row * 64 + col + 16] +
               stats[row * 64 + col + 32] + stats[row * 64 + col + 48];
    red[row][col] = s;
    __syncthreads();
    if (t < 16) {
        double tot = 0.0;
#pragma unroll
        for (int i = 0; i < 16; i++) tot += red[t][i];
        red[t][0] = tot;
    }
    __syncthreads();
    if (t < 8) {
        double N = (double)NPX;
        double mean = red[t][0] / N;
        double var = red[8 + t][0] / N - mean * mean;
        double scale = (double)gamma[t] / sqrt(var + 1e-5);
        ss[t] = (float)scale;
        ss[8 + t] = (float)((double)beta[t] - mean * scale);
    }
}

// ---------------------------------------------------------------------------
__global__ void k_norm(float* __restrict__ out, const float* __restrict__ ss) {
    int i = blockIdx.x * 256 + threadIdx.x;
    if (i < (BN * 8 * HW) / 4) {
        int plane = (i * 4) / HW;
        int ch = plane & 7;
        float sc = ss[ch], sh = ss[8 + ch];
        float4* p = (float4*)out + i;
        float4 v = *p;
        v.x = v.x * sc + sh;
        v.y = v.y * sc + sh;
        v.z = v.z * sc + sh;
        v.w = v.w * sc + sh;
        *p = v;
    }
}

// ---------------------------------------------------------------------------
extern "C" void kernel_launch(void* const* d_in, const int* in_sizes, int n_in,
                              void* d_out, int out_size, void* d_ws, size_t ws_size,
                              hipStream_t stream) {
    const float* x = (const float*)d_in[0];
    const float* w5 = (const float*)d_in[1];
    const float* b5 = (const float*)d_in[2];
    const float* w10 = (const float*)d_in[3];
    const float* b10 = (const float*)d_in[4];
    const float* w15 = (const float*)d_in[5];
    const float* b15 = (const float*)d_in[6];
    const float* gw = (const float*)d_in[7];
    const float* gb = (const float*)d_in[8];
    const float* mw = (const float*)d_in[9];
    const float* mb = (const float*)d_in[10];
    const float* gamma = (const float*)d_in[11];
    const float* beta = (const float*)d_in[12];

    float* out = (float*)d_out;
    unsigned short* p5i = (unsigned short*)((char*)d_ws + P5I_BYTE_OFF);
    unsigned short* p10i = (unsigned short*)((char*)d_ws + P10I_BYTE_OFF);
    unsigned short* p15i = (unsigned short*)((char*)d_ws + P15I_BYTE_OFF);
    short* cBg = (short*)((char*)d_ws + CWB_BYTE_OFF);
    short* gBg = (short*)((char*)d_ws + GWB_BYTE_OFF);
    double* stats = (double*)((char*)d_ws + STAT_BYTE_OFF);
    float* ss = (float*)((char*)d_ws + SS_BYTE_OFF);
    unsigned short* xbf = (unsigned short*)((char*)d_ws + XBF_BYTE_OFF);

    const bool use_xbf = (ws_size >= XBF_END);

    dim3 grid(GX, GY, BN);
    if (use_xbf) {
        // setup folded into k_xbf (consumers are later dispatches)
        k_xbf<<<dim3(352, 32), 256, 0, stream>>>(x, xbf, w5, w10, w15, gw, mw,
                                                 cBg, gBg, stats);
        k_pool5b<<<450, 256, 0, stream>>>(xbf, p5i);
        k_poolD<<<1300, 256, 0, stream>>>(p5i, p10i, p15i);
        k_fused<true><<<grid, 256, 0, stream>>>(x, xbf, p5i, p10i, p15i,
                                                (const unsigned short*)cBg, (const unsigned short*)gBg,
                                                b5, b10, b15, gb, mb, out, stats);
    } else {
        k_setup<<<1, 256, 0, stream>>>(w5, w10, w15, gw, mw, cBg, gBg, stats);
        k_pool5<<<3600, 256, 0, stream>>>(x, p5i);
        k_poolD<<<1300, 256, 0, stream>>>(p5i, p10i, p15i);
        k_fused<false><<<grid, 256, 0, stream>>>(x, xbf, p5i, p10i, p15i,
                                                 (const unsigned short*)cBg, (const unsigned short*)gBg,
                                                 b5, b10, b15, gb, mb, out, stats);
    }
    k_stats<<<1, 256, 0, stream>>>(stats, gamma, beta, ss);
    k_norm<<<(BN * 8 * HW / 4 + 255) / 256, 256, 0, stream>>>(out, ss);
}